// Round 1
// baseline (832.321 us; speedup 1.0000x reference)
//
#include <hip/hip_runtime.h>
#include <cmath>

typedef __bf16 bf16;
typedef __bf16 bf16x8 __attribute__((ext_vector_type(8)));
typedef __bf16 bf16x4 __attribute__((ext_vector_type(4)));
typedef float floatx4 __attribute__((ext_vector_type(4)));

#define E_ 8
#define M_ 2048
#define D_ 1024
#define F_ 4096

__device__ __forceinline__ void async16(const void* g, void* l) {
    __builtin_amdgcn_global_load_lds((const __attribute__((address_space(1))) unsigned int*)g,
                                     (__attribute__((address_space(3))) unsigned int*)l, 16, 0, 0);
}

// ---------------- fp32 -> bf16 elementwise ----------------
__global__ __launch_bounds__(256) void cvt_bf16_kernel(const float4* __restrict__ in,
                                                       bf16x4* __restrict__ out, int n4) {
    int i = blockIdx.x * 256 + threadIdx.x;
    int stride = gridDim.x * 256;
    for (; i < n4; i += stride) {
        float4 v = in[i];
        bf16x4 r = {(bf16)v.x, (bf16)v.y, (bf16)v.z, (bf16)v.w};
        out[i] = r;
    }
}

// ---------------- fp32 [R,C] -> bf16 transposed [C,R], per expert (blockIdx.z) ----------------
__global__ __launch_bounds__(256) void tconv_kernel(const float* __restrict__ in,
                                                    bf16* __restrict__ out, int R, int C) {
    __shared__ float t[32][33];
    size_t eoff = (size_t)blockIdx.z * R * C;
    in += eoff;
    out += eoff;
    int c0 = blockIdx.x * 32, r0 = blockIdx.y * 32;
    int tx = threadIdx.x, ty = threadIdx.y;  // 32 x 8
#pragma unroll
    for (int i = 0; i < 32; i += 8)
        t[ty + i][tx] = in[(size_t)(r0 + ty + i) * C + (c0 + tx)];
    __syncthreads();
#pragma unroll
    for (int i = 0; i < 32; i += 8)
        out[(size_t)(c0 + ty + i) * R + (r0 + tx)] = (bf16)t[tx][ty + i];
}

// ---------------- bf16 GEMM, B supplied transposed [N,K]; m97-style structure ----------------
// C[m,n] = sum_k A[m,k] * Bt[n,k] + bias[n]; optional exact-erf GELU fused, bf16 or f32 out.
template <bool GELU>
__global__ __launch_bounds__(256) void gemm_bt(const bf16* __restrict__ A,
                                               const bf16* __restrict__ Bt,
                                               const float* __restrict__ bias,
                                               void* __restrict__ Out,
                                               int M, int N, int K) {
    constexpr int BM = 128, BN = 128, BK = 32;
    __shared__ __align__(16) bf16 As[BM * BK];  // 8 KB, row-major [BM][BK]
    __shared__ __align__(16) bf16 Bs[BN * BK];  // 8 KB, row-major [BN][BK]

    const int e = blockIdx.z;
    A += (size_t)e * M * K;
    Bt += (size_t)e * N * K;
    bias += (size_t)e * N;

    const int rowBase = blockIdx.y * BM;
    const int colBase = blockIdx.x * BN;

    const int tid = threadIdx.x;  // 0..255, 4 waves
    const int wid = tid >> 6;
    const int lm = tid & 15;       // lane & 15
    const int lq = (tid & 63) >> 4;  // quad 0..3

    // staging: chunk ch (0..511) -> row = ch>>2, 8-elem colchunk q = ch&3
    // inst0: ch = tid, inst1: ch = tid + 256. LDS slot = ch*16 bytes (contiguous, required by
    // global_load_lds wave-uniform-base + lane*16 semantics).
    const bf16* ag0 = A + (size_t)(rowBase + (tid >> 2)) * K + (tid & 3) * 8;
    const bf16* ag1 = A + (size_t)(rowBase + ((tid + 256) >> 2)) * K + (tid & 3) * 8;
    const bf16* bg0 = Bt + (size_t)(colBase + (tid >> 2)) * K + (tid & 3) * 8;
    const bf16* bg1 = Bt + (size_t)(colBase + ((tid + 256) >> 2)) * K + (tid & 3) * 8;

    char* asb = (char*)As;
    char* bsb = (char*)Bs;
    void* al0 = asb + wid * 1024;         // wave-uniform LDS base, HW adds lane*16
    void* al1 = asb + 4096 + wid * 1024;
    void* bl0 = bsb + wid * 1024;
    void* bl1 = bsb + 4096 + wid * 1024;

    // wave 2x2 tiling of the 128x128 block: each wave owns 64x64 = 4x4 MFMA tiles
    const int wrow = (wid >> 1) * 64;
    const int wcol = (wid & 1) * 64;

    int aoff[4], boff[4];
#pragma unroll
    for (int i = 0; i < 4; ++i) {
        aoff[i] = (wrow + i * 16 + lm) * BK + lq * 8;  // A frag: A[m=lm][k=lq*8+j]
        boff[i] = (wcol + i * 16 + lm) * BK + lq * 8;  // B frag: B[k=lq*8+j][n=lm] via Bt[n][k]
    }

    floatx4 acc[4][4] = {};

    for (int k0 = 0; k0 < K; k0 += BK) {
        async16(ag0, al0);
        async16(ag1, al1);
        async16(bg0, bl0);
        async16(bg1, bl1);
        ag0 += BK; ag1 += BK; bg0 += BK; bg1 += BK;
        __syncthreads();  // drains vmcnt -> staging visible
        bf16x8 af[4], bfr[4];
#pragma unroll
        for (int i = 0; i < 4; ++i) af[i] = *(const bf16x8*)(As + aoff[i]);
#pragma unroll
        for (int i = 0; i < 4; ++i) bfr[i] = *(const bf16x8*)(Bs + boff[i]);
#pragma unroll
        for (int mi = 0; mi < 4; ++mi)
#pragma unroll
            for (int ni = 0; ni < 4; ++ni)
                acc[mi][ni] = __builtin_amdgcn_mfma_f32_16x16x32_bf16(af[mi], bfr[ni],
                                                                      acc[mi][ni], 0, 0, 0);
        __syncthreads();  // protect LDS before next overwrite
    }

    // epilogue: C/D layout col = lane&15, row = quad*4 + reg
    const size_t outBase = (size_t)e * M * N;
#pragma unroll
    for (int ni = 0; ni < 4; ++ni) {
        const int col = colBase + wcol + ni * 16 + lm;
        const float bv = bias[col];
#pragma unroll
        for (int mi = 0; mi < 4; ++mi) {
            const int row0 = rowBase + wrow + mi * 16 + lq * 4;
#pragma unroll
            for (int r = 0; r < 4; ++r) {
                float v = acc[mi][ni][r] + bv;
                if (GELU) {
                    v = 0.5f * v * (1.0f + erff(v * 0.70710678118654752f));
                    ((bf16*)Out)[outBase + (size_t)(row0 + r) * N + col] = (bf16)v;
                } else {
                    ((float*)Out)[outBase + (size_t)(row0 + r) * N + col] = v;
                }
            }
        }
    }
}

extern "C" void kernel_launch(void* const* d_in, const int* in_sizes, int n_in,
                              void* d_out, int out_size, void* d_ws, size_t ws_size,
                              hipStream_t stream) {
    const float* x = (const float*)d_in[0];
    const float* c_fc = (const float*)d_in[1];
    const float* c_proj = (const float*)d_in[2];
    const float* fc_bias = (const float*)d_in[3];
    const float* proj_bias = (const float*)d_in[4];
    float* out = (float*)d_out;

    // ws layout (bf16): xb [E,M,D] | wT [E, *, *] (cfcT then cprojT, same size) | h [E,M,F]
    bf16* xb = (bf16*)d_ws;
    bf16* wT = xb + (size_t)E_ * M_ * D_;
    bf16* h = wT + (size_t)E_ * D_ * F_;
    size_t need = ((size_t)E_ * M_ * D_ + (size_t)E_ * D_ * F_ + (size_t)E_ * M_ * F_) * 2;
    if (ws_size < need) return;  // insufficient scratch -> recognizable failure signature

    // 1. x -> bf16
    cvt_bf16_kernel<<<4096, 256, 0, stream>>>((const float4*)x, (bf16x4*)xb, E_ * M_ * D_ / 4);
    // 2. c_fc [E,D,F] -> wT = c_fc^T [E,F,D] bf16
    tconv_kernel<<<dim3(F_ / 32, D_ / 32, E_), dim3(32, 8), 0, stream>>>(c_fc, wT, D_, F_);
    // 3. h = gelu(xb @ c_fc + fc_bias), bf16
    gemm_bt<true><<<dim3(F_ / 128, M_ / 128, E_), 256, 0, stream>>>(xb, wT, fc_bias, h,
                                                                    M_, F_, D_);
    // 4. c_proj [E,F,D] -> wT = c_proj^T [E,D,F] bf16 (reuses region; stream-ordered)
    tconv_kernel<<<dim3(D_ / 32, F_ / 32, E_), dim3(32, 8), 0, stream>>>(c_proj, wT, F_, D_);
    // 5. out = h @ c_proj + proj_bias, fp32
    gemm_bt<false><<<dim3(D_ / 128, M_ / 128, E_), 256, 0, stream>>>(h, wT, proj_bias, out,
                                                                     M_, D_, F_);
}

// Round 2
// 791.568 us; speedup vs baseline: 1.0515x; 1.0515x over previous
//
#include <hip/hip_runtime.h>
#include <cmath>

typedef __bf16 bf16;
typedef __bf16 bf16x8 __attribute__((ext_vector_type(8)));
typedef __bf16 bf16x4 __attribute__((ext_vector_type(4)));
typedef float floatx4 __attribute__((ext_vector_type(4)));

#define E_ 8
#define M_ 2048
#define D_ 1024
#define F_ 4096

__device__ __forceinline__ void async16(const void* g, void* l) {
    __builtin_amdgcn_global_load_lds((const __attribute__((address_space(1))) unsigned int*)g,
                                     (__attribute__((address_space(3))) unsigned int*)l, 16, 0, 0);
}

// tanh-approx GELU: x * sigmoid(1.59577x + 0.0713548x^3). Max dev from exact ~3e-3.
__device__ __forceinline__ float gelu_fast(float u) {
    float s = u * (-1.5957691216f - 0.0713548162726f * u * u);
    return u * __builtin_amdgcn_rcpf(1.0f + __expf(s));
}

// ---------------- fp32 -> bf16 elementwise ----------------
__global__ __launch_bounds__(256) void cvt_bf16_kernel(const float4* __restrict__ in,
                                                       bf16x4* __restrict__ out, int n4) {
    int i = blockIdx.x * 256 + threadIdx.x;
    int stride = gridDim.x * 256;
    for (; i < n4; i += stride) {
        float4 v = in[i];
        bf16x4 r = {(bf16)v.x, (bf16)v.y, (bf16)v.z, (bf16)v.w};
        out[i] = r;
    }
}

// ---- fp32 [R,C] -> bf16 transposed [C,R], per expert (blockIdx.z). 64x64 tiles. ----
// Reads float4-coalesced; writes bf16x4 (8B) -> 128B contiguous per 16 lanes.
__global__ __launch_bounds__(256) void tconv_kernel(const float* __restrict__ in,
                                                    bf16* __restrict__ out, int R, int C) {
    __shared__ float t[64][65];
    size_t eoff = (size_t)blockIdx.z * R * C;
    in += eoff;
    out += eoff;
    const int c0 = blockIdx.x * 64, r0 = blockIdx.y * 64;
    const int tid = threadIdx.x;
    const int f4c = tid & 15;   // float4 column 0..15
    const int rsub = tid >> 4;  // 0..15
#pragma unroll
    for (int p = 0; p < 4; ++p) {
        int row = rsub + p * 16;
        float4 v = *(const float4*)&in[(size_t)(r0 + row) * C + c0 + f4c * 4];
        t[row][f4c * 4 + 0] = v.x;
        t[row][f4c * 4 + 1] = v.y;
        t[row][f4c * 4 + 2] = v.z;
        t[row][f4c * 4 + 3] = v.w;
    }
    __syncthreads();
    const int rr = (tid & 15) * 4;  // 4 source rows -> 4 consecutive out elements
#pragma unroll
    for (int p = 0; p < 4; ++p) {
        int c = (tid >> 4) + p * 16;
        bf16x4 o = {(bf16)t[rr + 0][c], (bf16)t[rr + 1][c], (bf16)t[rr + 2][c],
                    (bf16)t[rr + 3][c]};
        *(bf16x4*)&out[(size_t)(c0 + c) * R + r0 + rr] = o;
    }
}

// ---------------- bf16 GEMM, B supplied transposed [N,K]; m97-style structure ----------------
// XOR-swizzled LDS chunk map: slot(row,kchunk) = row*4 + (kchunk ^ ((row>>2)&3)).
// Staging permutes per-lane global k-chunk (coalescing unchanged); fragment reads become
// bank-conflict-free (each of 8 bank-groups gets exactly 4 lanes per 32-lane half).
template <bool GELU>
__global__ __launch_bounds__(256) void gemm_bt(const bf16* __restrict__ A,
                                               const bf16* __restrict__ Bt,
                                               const float* __restrict__ bias,
                                               void* __restrict__ Out,
                                               int M, int N, int K) {
    constexpr int BM = 128, BN = 128, BK = 32;
    __shared__ __align__(16) bf16 As[BM * BK];  // 8 KB
    __shared__ __align__(16) bf16 Bs[BN * BK];  // 8 KB

    const int e = blockIdx.z;
    A += (size_t)e * M * K;
    Bt += (size_t)e * N * K;
    bias += (size_t)e * N;

    const int rowBase = blockIdx.y * BM;
    const int colBase = blockIdx.x * BN;

    const int tid = threadIdx.x;
    const int wid = tid >> 6;
    const int lm = tid & 15;
    const int lq = (tid & 63) >> 4;

    // staging: slot s holds global (row = s>>2, kchunk = (s&3) ^ ((s>>4)&3))
    const int kperm = ((tid & 3) ^ ((tid >> 4) & 3)) * 8;
    const bf16* ag0 = A + (size_t)(rowBase + (tid >> 2)) * K + kperm;
    const bf16* ag1 = A + (size_t)(rowBase + (tid >> 2) + 64) * K + kperm;
    const bf16* bg0 = Bt + (size_t)(colBase + (tid >> 2)) * K + kperm;
    const bf16* bg1 = Bt + (size_t)(colBase + (tid >> 2) + 64) * K + kperm;

    char* asb = (char*)As;
    char* bsb = (char*)Bs;
    void* al0 = asb + wid * 1024;  // wave-uniform base; HW adds lane*16
    void* al1 = asb + 4096 + wid * 1024;
    void* bl0 = bsb + wid * 1024;
    void* bl1 = bsb + 4096 + wid * 1024;

    const int wrow = (wid >> 1) * 64;
    const int wcol = (wid & 1) * 64;

    int aoff[4], boff[4];
#pragma unroll
    for (int i = 0; i < 4; ++i) {
        // fragment (row = wrow+i*16+lm, kchunk lq) lives at swizzled slot:
        // elem offset = row*BK + (lq ^ ((row>>2)&3))*8; (row>>2)&3 == lm>>2 here.
        aoff[i] = (wrow + i * 16 + lm) * BK + (lq ^ (lm >> 2)) * 8;
        boff[i] = (wcol + i * 16 + lm) * BK + (lq ^ (lm >> 2)) * 8;
    }

    floatx4 acc[4][4] = {};

    for (int k0 = 0; k0 < K; k0 += BK) {
        async16(ag0, al0);
        async16(ag1, al1);
        async16(bg0, bl0);
        async16(bg1, bl1);
        ag0 += BK; ag1 += BK; bg0 += BK; bg1 += BK;
        __syncthreads();
        bf16x8 af[4], bfr[4];
#pragma unroll
        for (int i = 0; i < 4; ++i) af[i] = *(const bf16x8*)(As + aoff[i]);
#pragma unroll
        for (int i = 0; i < 4; ++i) bfr[i] = *(const bf16x8*)(Bs + boff[i]);
#pragma unroll
        for (int mi = 0; mi < 4; ++mi)
#pragma unroll
            for (int ni = 0; ni < 4; ++ni)
                acc[mi][ni] = __builtin_amdgcn_mfma_f32_16x16x32_bf16(af[mi], bfr[ni],
                                                                      acc[mi][ni], 0, 0, 0);
        __syncthreads();
    }

    // epilogue: C/D layout col = lane&15, row = quad*4 + reg
    const size_t outBase = (size_t)e * M * N;
#pragma unroll
    for (int ni = 0; ni < 4; ++ni) {
        const int col = colBase + wcol + ni * 16 + lm;
        const float bv = bias[col];
#pragma unroll
        for (int mi = 0; mi < 4; ++mi) {
            const int row0 = rowBase + wrow + mi * 16 + lq * 4;
#pragma unroll
            for (int r = 0; r < 4; ++r) {
                float v = acc[mi][ni][r] + bv;
                if (GELU) {
                    v = gelu_fast(v);
                    ((bf16*)Out)[outBase + (size_t)(row0 + r) * N + col] = (bf16)v;
                } else {
                    ((float*)Out)[outBase + (size_t)(row0 + r) * N + col] = v;
                }
            }
        }
    }
}

extern "C" void kernel_launch(void* const* d_in, const int* in_sizes, int n_in,
                              void* d_out, int out_size, void* d_ws, size_t ws_size,
                              hipStream_t stream) {
    const float* x = (const float*)d_in[0];
    const float* c_fc = (const float*)d_in[1];
    const float* c_proj = (const float*)d_in[2];
    const float* fc_bias = (const float*)d_in[3];
    const float* proj_bias = (const float*)d_in[4];
    float* out = (float*)d_out;

    bf16* xb = (bf16*)d_ws;
    bf16* wT = xb + (size_t)E_ * M_ * D_;
    bf16* h = wT + (size_t)E_ * D_ * F_;
    size_t need = ((size_t)E_ * M_ * D_ + (size_t)E_ * D_ * F_ + (size_t)E_ * M_ * F_) * 2;
    if (ws_size < need) return;

    cvt_bf16_kernel<<<4096, 256, 0, stream>>>((const float4*)x, (bf16x4*)xb, E_ * M_ * D_ / 4);
    tconv_kernel<<<dim3(F_ / 64, D_ / 64, E_), 256, 0, stream>>>(c_fc, wT, D_, F_);
    gemm_bt<true><<<dim3(F_ / 128, M_ / 128, E_), 256, 0, stream>>>(xb, wT, fc_bias, h,
                                                                    M_, F_, D_);
    tconv_kernel<<<dim3(D_ / 64, F_ / 64, E_), 256, 0, stream>>>(c_proj, wT, F_, D_);
    gemm_bt<false><<<dim3(D_ / 128, M_ / 128, E_), 256, 0, stream>>>(h, wT, proj_bias, out,
                                                                     M_, D_, F_);
}

// Round 3
// 763.881 us; speedup vs baseline: 1.0896x; 1.0362x over previous
//
#include <hip/hip_runtime.h>
#include <cmath>

typedef __bf16 bf16;
typedef __bf16 bf16x8 __attribute__((ext_vector_type(8)));
typedef __bf16 bf16x4 __attribute__((ext_vector_type(4)));
typedef float floatx4 __attribute__((ext_vector_type(4)));

#define E_ 8
#define M_ 2048
#define D_ 1024
#define F_ 4096

__device__ __forceinline__ void async16(const void* g, void* l) {
    __builtin_amdgcn_global_load_lds((const __attribute__((address_space(1))) unsigned int*)g,
                                     (__attribute__((address_space(3))) unsigned int*)l, 16, 0, 0);
}

// tanh-approx GELU: x * sigmoid(1.59577x + 0.0713548x^3). Max dev from exact ~3e-3.
__device__ __forceinline__ float gelu_fast(float u) {
    float s = u * (-1.5957691216f - 0.0713548162726f * u * u);
    return u * __builtin_amdgcn_rcpf(1.0f + __expf(s));
}

// ---------------- fp32 -> bf16 elementwise, 16B stores ----------------
__global__ __launch_bounds__(256) void cvt_bf16_kernel(const float4* __restrict__ in,
                                                       bf16x8* __restrict__ out, int n8) {
    int i = blockIdx.x * 256 + threadIdx.x;
    int stride = gridDim.x * 256;
    for (; i < n8; i += stride) {
        float4 a = in[2 * i], b = in[2 * i + 1];
        bf16x8 r = {(bf16)a.x, (bf16)a.y, (bf16)a.z, (bf16)a.w,
                    (bf16)b.x, (bf16)b.y, (bf16)b.z, (bf16)b.w};
        out[i] = r;
    }
}

// ---- fp32 [R,C] -> bf16 transposed [C,R], per expert (blockIdx.z). 64x64 tiles. ----
// float4-coalesced reads; bf16x8 (16B) stores -> 128B contiguous per 8 lanes.
__global__ __launch_bounds__(256) void tconv_kernel(const float* __restrict__ in,
                                                    bf16* __restrict__ out, int R, int C) {
    __shared__ float t[64][65];
    size_t eoff = (size_t)blockIdx.z * R * C;
    in += eoff;
    out += eoff;
    const int c0 = blockIdx.x * 64, r0 = blockIdx.y * 64;
    const int tid = threadIdx.x;
    const int f4c = tid & 15;
    const int rsub = tid >> 4;
#pragma unroll
    for (int p = 0; p < 4; ++p) {
        int row = rsub + p * 16;
        float4 v = *(const float4*)&in[(size_t)(r0 + row) * C + c0 + f4c * 4];
        t[row][f4c * 4 + 0] = v.x;
        t[row][f4c * 4 + 1] = v.y;
        t[row][f4c * 4 + 2] = v.z;
        t[row][f4c * 4 + 3] = v.w;
    }
    __syncthreads();
    const int rr = (tid & 7) * 8;  // 8 source rows -> 8 consecutive out elems
    const int cbase = tid >> 3;    // 0..31
#pragma unroll
    for (int p = 0; p < 2; ++p) {
        int c = cbase + p * 32;
        bf16x8 o = {(bf16)t[rr + 0][c], (bf16)t[rr + 1][c], (bf16)t[rr + 2][c],
                    (bf16)t[rr + 3][c], (bf16)t[rr + 4][c], (bf16)t[rr + 5][c],
                    (bf16)t[rr + 6][c], (bf16)t[rr + 7][c]};
        *(bf16x8*)&out[(size_t)(c0 + c) * R + r0 + rr] = o;
    }
}

// ---------------- bf16 GEMM, B supplied transposed [N,K] ----------------
// Double-buffered LDS (one barrier/iter, prefetch-then-compute) + XCD-aware block remap:
// M-tile index is fastest-varying -> same-XCD-consecutive blocks (stride-8 round robin)
// share A panels and stream the same B panels (live set ~3MB < 4MB XCD L2).
template <bool GELU>
__global__ __launch_bounds__(256) void gemm_bt(const bf16* __restrict__ A,
                                               const bf16* __restrict__ Bt,
                                               const float* __restrict__ bias,
                                               void* __restrict__ Out,
                                               int M, int N, int K) {
    constexpr int BM = 128, BN = 128, BK = 32;
    __shared__ __align__(16) bf16 As[2][BM * BK];  // 2 x 8 KB
    __shared__ __align__(16) bf16 Bs[2][BN * BK];  // 2 x 8 KB

    // remap: y (M-tile, 16 of them) fastest
    const int b = blockIdx.x + gridDim.x * (blockIdx.y + 16 * blockIdx.z);
    const int ty = b & 15;
    const int tx = (b >> 4) % gridDim.x;
    const int e = (b >> 4) / gridDim.x;

    A += (size_t)e * M * K;
    Bt += (size_t)e * N * K;
    bias += (size_t)e * N;

    const int rowBase = ty * BM;
    const int colBase = tx * BN;

    const int tid = threadIdx.x;
    const int wid = tid >> 6;
    const int lm = tid & 15;
    const int lq = (tid & 63) >> 4;

    // staging: slot s holds global (row = s>>2, kchunk = (s&3) ^ ((s>>4)&3))
    const int kperm = ((tid & 3) ^ ((tid >> 4) & 3)) * 8;
    const bf16* ag0 = A + (size_t)(rowBase + (tid >> 2)) * K + kperm;
    const bf16* ag1 = A + (size_t)(rowBase + (tid >> 2) + 64) * K + kperm;
    const bf16* bg0 = Bt + (size_t)(colBase + (tid >> 2)) * K + kperm;
    const bf16* bg1 = Bt + (size_t)(colBase + (tid >> 2) + 64) * K + kperm;

    auto stage = [&](int buf) {
        char* ab = (char*)As[buf];
        char* bb = (char*)Bs[buf];
        async16(ag0, ab + wid * 1024);
        async16(ag1, ab + 4096 + wid * 1024);
        async16(bg0, bb + wid * 1024);
        async16(bg1, bb + 4096 + wid * 1024);
        ag0 += BK; ag1 += BK; bg0 += BK; bg1 += BK;
    };

    const int wrow = (wid >> 1) * 64;
    const int wcol = (wid & 1) * 64;

    int aoff[4], boff[4];
#pragma unroll
    for (int i = 0; i < 4; ++i) {
        aoff[i] = (wrow + i * 16 + lm) * BK + (lq ^ (lm >> 2)) * 8;
        boff[i] = (wcol + i * 16 + lm) * BK + (lq ^ (lm >> 2)) * 8;
    }

    floatx4 acc[4][4] = {};
    const int nIter = K / BK;

    stage(0);
    __syncthreads();  // tile 0 visible

    for (int it = 0; it < nIter; ++it) {
        const int cur = it & 1;
        if (it + 1 < nIter) stage(cur ^ 1);  // prefetch next tile into other buffer
        bf16x8 af[4], bfr[4];
#pragma unroll
        for (int i = 0; i < 4; ++i) af[i] = *(const bf16x8*)(As[cur] + aoff[i]);
#pragma unroll
        for (int i = 0; i < 4; ++i) bfr[i] = *(const bf16x8*)(Bs[cur] + boff[i]);
#pragma unroll
        for (int mi = 0; mi < 4; ++mi)
#pragma unroll
            for (int ni = 0; ni < 4; ++ni)
                acc[mi][ni] = __builtin_amdgcn_mfma_f32_16x16x32_bf16(af[mi], bfr[ni],
                                                                      acc[mi][ni], 0, 0, 0);
        __syncthreads();  // drains prefetch + protects cur for next overwrite
    }

    // epilogue: C/D layout col = lane&15, row = quad*4 + reg
    const size_t outBase = (size_t)e * M * N;
#pragma unroll
    for (int ni = 0; ni < 4; ++ni) {
        const int col = colBase + wcol + ni * 16 + lm;
        const float bv = bias[col];
#pragma unroll
        for (int mi = 0; mi < 4; ++mi) {
            const int row0 = rowBase + wrow + mi * 16 + lq * 4;
#pragma unroll
            for (int r = 0; r < 4; ++r) {
                float v = acc[mi][ni][r] + bv;
                if (GELU) {
                    v = gelu_fast(v);
                    ((bf16*)Out)[outBase + (size_t)(row0 + r) * N + col] = (bf16)v;
                } else {
                    ((float*)Out)[outBase + (size_t)(row0 + r) * N + col] = v;
                }
            }
        }
    }
}

extern "C" void kernel_launch(void* const* d_in, const int* in_sizes, int n_in,
                              void* d_out, int out_size, void* d_ws, size_t ws_size,
                              hipStream_t stream) {
    const float* x = (const float*)d_in[0];
    const float* c_fc = (const float*)d_in[1];
    const float* c_proj = (const float*)d_in[2];
    const float* fc_bias = (const float*)d_in[3];
    const float* proj_bias = (const float*)d_in[4];
    float* out = (float*)d_out;

    bf16* xb = (bf16*)d_ws;
    bf16* wT = xb + (size_t)E_ * M_ * D_;
    bf16* h = wT + (size_t)E_ * D_ * F_;
    size_t need = ((size_t)E_ * M_ * D_ + (size_t)E_ * D_ * F_ + (size_t)E_ * M_ * F_) * 2;
    if (ws_size < need) return;

    cvt_bf16_kernel<<<2048, 256, 0, stream>>>((const float4*)x, (bf16x8*)xb, E_ * M_ * D_ / 8);
    tconv_kernel<<<dim3(F_ / 64, D_ / 64, E_), 256, 0, stream>>>(c_fc, wT, D_, F_);
    gemm_bt<true><<<dim3(F_ / 128, M_ / 128, E_), 256, 0, stream>>>(xb, wT, fc_bias, h,
                                                                    M_, F_, D_);
    tconv_kernel<<<dim3(D_ / 64, F_ / 64, E_), 256, 0, stream>>>(c_proj, wT, F_, D_);
    gemm_bt<false><<<dim3(D_ / 128, M_ / 128, E_), 256, 0, stream>>>(h, wT, proj_bias, out,
                                                                     M_, D_, F_);
}